// Round 7
// baseline (188.482 us; speedup 1.0000x reference)
//
#include <hip/hip_runtime.h>

// SAGEConv — fp8-gather + fused aggregate/GEMM, fixed-capacity buckets.
// R13 post-mortem: spill gone (WRITE 359->50MB, FETCH 326->107MB) but k_agg
// 63.5us (8-lane regroup bought nothing; VALUBusy 23%). Ledger across R8-R13
// fits: total = kernels + ~60us FIXED per-iteration cost (graph/gaps/memset)
// -> explains R11 fusion saving only 6us. Controllable budget: prep ~58 +
// agg ~63.5.
// R14: (1) split prep back into k_part + k_cvt (+3us) so next profile shows
// ALL kernels' real durations (tests fixed-overhead model; locates prep's
// time — bet: k_part scatter). (2) k_agg Phase B 6-deep chains (~56 VGPR,
// under the 64-VGPR occupancy cliff, keeps 4 blocks/CU). Predict k_agg ~52,
// k_part ~30-50 visible, k_cvt ~13, total ~175.

constexpr int NN = 100000;
constexpr int NE = 1600000;
constexpr int D  = 128;
constexpr int BK = 64;                      // nodes per bucket
constexpr int NB = (NN + BK - 1) / BK;      // 1563 buckets
constexpr int PB = 8192;                    // edges per partition block
constexpr int CAPB = 1536;                  // fixed bucket capacity (mean 1024, sd 32)
constexpr int XST = 258;                    // Xs row stride (shorts): 516B -> +1-pad
constexpr int PADI = 32;                    // ints per bucket counter slot (128B line)
constexpr int PART_BLOCKS = (NE + PB - 1) / PB;   // 196
constexpr int WPK_BLOCKS  = 16;
constexpr int CVT_BLOCKS  = NN * D / 8 / 256;     // 6250

typedef __attribute__((ext_vector_type(8))) short short8;   // 8 bf16 (4 VGPR)
typedef __attribute__((ext_vector_type(4))) float floatx4;  // MFMA C/D
typedef __attribute__((ext_vector_type(2))) float floatx2;

static __device__ __forceinline__ unsigned short f2bf(float f) {
    unsigned u = __float_as_uint(f);
    unsigned r = ((u >> 16) & 1u) + 0x7fffu;
    return (unsigned short)((u + r) >> 16);
}

// ---------------------------------------------------------------------------
// k_cvt: blocks [0,6250): h fp32 -> fp8 stream; [6250,6266): pack Wcat bf16.
// ---------------------------------------------------------------------------
__global__ __launch_bounds__(256) void k_cvt(
    const float* __restrict__ h, const float* __restrict__ Wself,
    const float* __restrict__ Wneigh, uint2* __restrict__ hf8,
    unsigned short* __restrict__ Wp)
{
    const int t = threadIdx.x;
    if (blockIdx.x < CVT_BLOCKS) {
        int i = blockIdx.x * 256 + t;
        const float4* h4 = (const float4*)h;
        float4 a = h4[(size_t)i * 2];
        float4 b = h4[(size_t)i * 2 + 1];
        unsigned q0 = __builtin_amdgcn_cvt_pk_fp8_f32(a.x, a.y, 0u, false);
        q0          = __builtin_amdgcn_cvt_pk_fp8_f32(a.z, a.w, q0, true);
        unsigned q1 = __builtin_amdgcn_cvt_pk_fp8_f32(b.x, b.y, 0u, false);
        q1          = __builtin_amdgcn_cvt_pk_fp8_f32(b.z, b.w, q1, true);
        hf8[i] = make_uint2(q0, q1);
    } else {
        int kg  = (blockIdx.x - CVT_BLOCKS) * 2 + (t >> 7);   // 0..31
        int col = t & 127;
        unsigned short v[8];
#pragma unroll
        for (int j = 0; j < 8; ++j) {
            int k = kg * 8 + j;
            const float* W = (k < 128) ? (Wself + (size_t)k * D)
                                       : (Wneigh + (size_t)(k - 128) * D);
            v[j] = f2bf(W[col]);
        }
        uint4 o;
        o.x = (unsigned)v[0] | ((unsigned)v[1] << 16);
        o.y = (unsigned)v[2] | ((unsigned)v[3] << 16);
        o.z = (unsigned)v[4] | ((unsigned)v[5] << 16);
        o.w = (unsigned)v[6] | ((unsigned)v[7] << 16);
        ((uint4*)Wp)[kg * 128 + col] = o;
    }
}

// ---------------------------------------------------------------------------
// k_part: partition edges into fixed-capacity buckets packed[b*CAPB+rank].
// Batched loads, LDS hist, one padded reserve atomic per (block,bucket).
// ---------------------------------------------------------------------------
__global__ __launch_bounds__(256) void k_part(
    const int* __restrict__ src, const int* __restrict__ dst,
    int* __restrict__ bcursor, unsigned* __restrict__ packed)
{
    __shared__ int lh[NB];
    const int t = threadIdx.x;
    const int e0 = blockIdx.x * PB;

    for (int i = t; i < NB; i += 256) lh[i] = 0;
    __syncthreads();

    int myd[32], msrc[32];
#pragma unroll
    for (int j = 0; j < 32; ++j) {
        int e = e0 + j * 256 + t;
        myd[j] = (e < NE) ? dst[e] : -1;
    }
#pragma unroll
    for (int j = 0; j < 32; ++j) {
        int e = e0 + j * 256 + t;
        msrc[j] = (e < NE) ? src[e] : 0;
    }
#pragma unroll
    for (int j = 0; j < 32; ++j)
        if (myd[j] >= 0) atomicAdd(&lh[myd[j] >> 6], 1);
    __syncthreads();
    for (int i = t; i < NB; i += 256) {
        int c = lh[i];
        if (c) lh[i] = atomicAdd(&bcursor[(size_t)i * PADI], c);
    }
    __syncthreads();
#pragma unroll
    for (int j = 0; j < 32; ++j) {
        if (myd[j] >= 0) {
            int b = myd[j] >> 6;
            int pos = atomicAdd(&lh[b], 1);        // within-bucket rank
            if (pos < CAPB)
                packed[(size_t)b * CAPB + pos] =
                    (unsigned)msrc[j] | ((unsigned)(myd[j] & 63) << 17);
        }
    }
}

// ---------------------------------------------------------------------------
// Fused per-bucket kernel, 512 threads:
//   Phase 0: self rows fp32 -> bf16 -> Xs cols 0..127.
//   Phase A: counting-sort the bucket's edges into LDS (by dst&63).
//   Phase B: fp8 gather — 64 groups of 8 lanes; lane loads uint4 (16B);
//            6-deep chains (~56 VGPR, under 64-cliff); floatx2 accumulate;
//            mean bf16 -> Xs cols 128..255.
//   Phase C: pure-LDS MFMA out[64x128] = Xs(64x256) @ Wcat, 8 waves.
// LDS 39.0KB -> 4 blocks/CU if VGPR<=64.
// ---------------------------------------------------------------------------
__global__ __launch_bounds__(512) void k_agg_gemm(
    const float* __restrict__ h, const uint2* __restrict__ hf8,
    const int* __restrict__ bcursor, const unsigned* __restrict__ packed,
    const unsigned short* __restrict__ Wp, float* __restrict__ out)
{
    __shared__ unsigned short Xs[BK][XST];     // 32.2 KiB A-tile (bf16)
    __shared__ unsigned sorted[CAPB];          // 6 KiB
    __shared__ int cnt[BK], offs[BK], cur[BK];

    const int t      = threadIdx.x;
    const int bucket = blockIdx.x;
    const size_t ebeg = (size_t)bucket * CAPB;
    const int ecnt   = min(bcursor[(size_t)bucket * PADI], CAPB);

    if (t < BK) cnt[t] = 0;

    // ---- Phase 0: self rows fp32 -> bf16 into Xs cols 0..127 ----
    {
        int row = t >> 3, seg = t & 7;          // 64 rows x 8 segs of 16 floats
        int grow = min(bucket * BK + row, NN - 1);
        const float4* hp = (const float4*)(h + (size_t)grow * D + seg * 16);
        float4 f0 = hp[0], f1 = hp[1], f2 = hp[2], f3 = hp[3];
        uint4 q0, q1;
        q0.x = (unsigned)f2bf(f0.x) | ((unsigned)f2bf(f0.y) << 16);
        q0.y = (unsigned)f2bf(f0.z) | ((unsigned)f2bf(f0.w) << 16);
        q0.z = (unsigned)f2bf(f1.x) | ((unsigned)f2bf(f1.y) << 16);
        q0.w = (unsigned)f2bf(f1.z) | ((unsigned)f2bf(f1.w) << 16);
        q1.x = (unsigned)f2bf(f2.x) | ((unsigned)f2bf(f2.y) << 16);
        q1.y = (unsigned)f2bf(f2.z) | ((unsigned)f2bf(f2.w) << 16);
        q1.z = (unsigned)f2bf(f3.x) | ((unsigned)f2bf(f3.y) << 16);
        q1.w = (unsigned)f2bf(f3.z) | ((unsigned)f2bf(f3.w) << 16);
        *(uint4*)&Xs[row][seg * 16]     = q0;
        *(uint4*)&Xs[row][seg * 16 + 8] = q1;
    }
    __syncthreads();

    // ---- Phase A: counting sort of the bucket's edges into LDS ----
    unsigned pk[3];
#pragma unroll
    for (int i = 0; i < 3; ++i) {
        int idx = t + i * 512;
        pk[i] = (idx < ecnt) ? packed[ebeg + idx] : 0u;
    }
#pragma unroll
    for (int i = 0; i < 3; ++i) {
        int idx = t + i * 512;
        if (idx < ecnt) atomicAdd(&cnt[(pk[i] >> 17) & 63u], 1);
    }
    __syncthreads();
    if (t < BK) {                       // 64-wide shuffle scan (wave 0)
        int v = cnt[t];
        int sum = v;
#pragma unroll
        for (int off = 1; off < 64; off <<= 1) {
            int u = __shfl_up(sum, off, 64);
            if (t >= off) sum += u;
        }
        offs[t] = sum - v;
        cur[t]  = sum - v;
    }
    __syncthreads();
#pragma unroll
    for (int i = 0; i < 3; ++i) {
        int idx = t + i * 512;
        if (idx < ecnt) {
            int pos = atomicAdd(&cur[(pk[i] >> 17) & 63u], 1);
            sorted[pos] = pk[i] & 0x1FFFFu;
        }
    }
    __syncthreads();

    // ---- Phase B: fp8 gather, 8-lane groups, 6-deep, pk accumulate ----
    {
        const int g  = t >> 3;          // node 0..63 (one per group)
        const int l8 = t & 7;           // 16-feature slice
        const int beg = offs[g];
        const int n   = cnt[g];
        const uint4* __restrict__ hr = (const uint4*)hf8;   // 8 uint4 per row

        floatx2 ac[8];
#pragma unroll
        for (int j = 0; j < 8; ++j) ac[j] = (floatx2){0.f, 0.f};

#define ACC16(X) do {                                                         \
            unsigned ww0 = (X).x, ww1 = (X).y, ww2 = (X).z, ww3 = (X).w;      \
            ac[0] += __builtin_amdgcn_cvt_pk_f32_fp8(ww0, false);             \
            ac[1] += __builtin_amdgcn_cvt_pk_f32_fp8(ww0, true);              \
            ac[2] += __builtin_amdgcn_cvt_pk_f32_fp8(ww1, false);             \
            ac[3] += __builtin_amdgcn_cvt_pk_f32_fp8(ww1, true);              \
            ac[4] += __builtin_amdgcn_cvt_pk_f32_fp8(ww2, false);             \
            ac[5] += __builtin_amdgcn_cvt_pk_f32_fp8(ww2, true);              \
            ac[6] += __builtin_amdgcn_cvt_pk_f32_fp8(ww3, false);             \
            ac[7] += __builtin_amdgcn_cvt_pk_f32_fp8(ww3, true);              \
        } while (0)

        int e = 0;
        for (; e + 5 < n; e += 6) {
            uint4 x0 = hr[(size_t)sorted[beg + e]     * 8 + l8];
            uint4 x1 = hr[(size_t)sorted[beg + e + 1] * 8 + l8];
            uint4 x2 = hr[(size_t)sorted[beg + e + 2] * 8 + l8];
            uint4 x3 = hr[(size_t)sorted[beg + e + 3] * 8 + l8];
            uint4 x4 = hr[(size_t)sorted[beg + e + 4] * 8 + l8];
            uint4 x5 = hr[(size_t)sorted[beg + e + 5] * 8 + l8];
            ACC16(x0); ACC16(x1); ACC16(x2);
            ACC16(x3); ACC16(x4); ACC16(x5);
        }
        for (; e + 1 < n; e += 2) {
            uint4 x0 = hr[(size_t)sorted[beg + e]     * 8 + l8];
            uint4 x1 = hr[(size_t)sorted[beg + e + 1] * 8 + l8];
            ACC16(x0); ACC16(x1);
        }
        if (e < n) {
            uint4 x0 = hr[(size_t)sorted[beg + e] * 8 + l8];
            ACC16(x0);
        }
#undef ACC16

        float inv = (n > 0) ? 1.0f / (float)n : 0.0f;
        unsigned short m[16];
#pragma unroll
        for (int j = 0; j < 8; ++j) {
            m[j * 2]     = f2bf(ac[j].x * inv);
            m[j * 2 + 1] = f2bf(ac[j].y * inv);
        }
        uint4 o0, o1;
        o0.x = (unsigned)m[0]  | ((unsigned)m[1]  << 16);
        o0.y = (unsigned)m[2]  | ((unsigned)m[3]  << 16);
        o0.z = (unsigned)m[4]  | ((unsigned)m[5]  << 16);
        o0.w = (unsigned)m[6]  | ((unsigned)m[7]  << 16);
        o1.x = (unsigned)m[8]  | ((unsigned)m[9]  << 16);
        o1.y = (unsigned)m[10] | ((unsigned)m[11] << 16);
        o1.z = (unsigned)m[12] | ((unsigned)m[13] << 16);
        o1.w = (unsigned)m[14] | ((unsigned)m[15] << 16);
        *(uint4*)&Xs[g][128 + l8 * 16]     = o0;
        *(uint4*)&Xs[g][128 + l8 * 16 + 8] = o1;
    }
    __syncthreads();

    // ---- Phase C: MFMA  out[64x128] = Xs(64x256) @ Wcat(256x128), 8 waves -
    const int wave  = t >> 6;            // 0..7
    const int lane  = t & 63;
    const int wl16  = lane & 15;
    const int kg4   = lane >> 4;         // 0..3
    const int wrow  = wave & 3;          // row-group 0..3
    const int chalf = wave >> 2;         // col half 0/1
    floatx4 acc[4];
#pragma unroll
    for (int c = 0; c < 4; ++c) acc[c] = (floatx4){0.f, 0.f, 0.f, 0.f};

    const int arow = wrow * 16 + wl16;   // 0..63
#pragma unroll
    for (int ks = 0; ks < 8; ++ks) {
        const short8 a = *(const short8*)&Xs[arow][ks * 32 + kg4 * 8];
#pragma unroll
        for (int c = 0; c < 4; ++c) {
            const int ct = chalf * 4 + c;
            const short8 b = *(const short8*)(Wp + (((ks * 4 + kg4) * 128) + ct * 16 + wl16) * 8);
            acc[c] = __builtin_amdgcn_mfma_f32_16x16x32_bf16(a, b, acc[c], 0, 0, 0);
        }
    }

    // C/D layout: col = lane&15, row = (lane>>4)*4 + reg
    const int rbase = bucket * BK + wrow * 16 + kg4 * 4;
#pragma unroll
    for (int r = 0; r < 4; ++r) {
        int row = rbase + r;
        if (row < NN) {
            float* o = out + (size_t)row * D + chalf * 64 + wl16;
#pragma unroll
            for (int c = 0; c < 4; ++c)
                o[c * 16] = acc[c][r];
        }
    }
}

extern "C" void kernel_launch(void* const* d_in, const int* in_sizes, int n_in,
                              void* d_out, int out_size, void* d_ws, size_t ws_size,
                              hipStream_t stream) {
    const float* h      = (const float*)d_in[0];
    const int*   src    = (const int*)d_in[1];
    const int*   dst    = (const int*)d_in[2];
    const float* Wself  = (const float*)d_in[3];
    const float* Wneigh = (const float*)d_in[4];
    float*       out    = (float*)d_out;

    // workspace layout (~23 MB)
    uint2* hf8         = (uint2*)d_ws;                         // NN*D/8 uint2 (12.8MB)
    unsigned short* Wp = (unsigned short*)(hf8 + (size_t)NN * D / 8);  // 64KB
    unsigned* packed   = (unsigned*)(Wp + 256 * D);            // NB*CAPB (9.6MB)
    uintptr_t bc_a     = ((uintptr_t)(packed + (size_t)NB * CAPB) + 255) & ~(uintptr_t)255;
    int* bcursor       = (int*)bc_a;                           // NB*PADI (200KB, padded)

    hipMemsetAsync(bcursor, 0, (size_t)NB * PADI * sizeof(int), stream);

    k_cvt      <<<dim3(CVT_BLOCKS + WPK_BLOCKS), 256, 0, stream>>>(h, Wself, Wneigh, hf8, Wp);
    k_part     <<<dim3(PART_BLOCKS), 256, 0, stream>>>(src, dst, bcursor, packed);
    k_agg_gemm <<<dim3(NB), 512, 0, stream>>>(h, hf8, bcursor, packed, Wp, out);
}

// Round 8
// 186.149 us; speedup vs baseline: 1.0125x; 1.0125x over previous
//
#include <hip/hip_runtime.h>

// SAGEConv — fp8-gather + fused aggregate/GEMM + 2-pass radix partition.
// R14 post-mortem: 6-deep gave only ~3us (depth exhausted; VGPR 60).
// Ledger R11-vs-R14 under one fixed overhead resolves k_part ~= 55us and
// it is the prep wall even fused (R11 fusion saved only 6us). Mechanisms:
// ~6 serial reserve atomics/thread on 196-block-contended lines + 8192
// isolated 4B scatter stores/block into 1563 regions (8x write amp,
// cross-XCD line bouncing).
// R15: two-pass radix: P1 (fused w/ cvt+Wpack): 49 super-buckets (dst>>11),
// LDS counting sort -> ~670B contiguous run writes, 9.6K reserves total.
// P2: 49x5 chunk blocks, 32-wide fine sort -> ~1KB runs, ~5-block/line
// contention. Output format identical for k_agg (unchanged R14 version).
// Predict part 55 -> ~15; total 188.5 -> ~150.

constexpr int NN = 100000;
constexpr int NE = 1600000;
constexpr int D  = 128;
constexpr int BK = 64;                      // nodes per bucket
constexpr int NB = (NN + BK - 1) / BK;      // 1563 fine buckets
constexpr int NS = (NN + 2047) / 2048;      // 49 super-buckets (dst>>11)
constexpr int PB = 8192;                    // edges per partition block
constexpr int CAPB = 1536;                  // fine capacity (mean 1024, sd 32)
constexpr int CAPS = 40960;                 // super capacity (mean 32768, sd 181)
constexpr int CHUNKS = CAPS / PB;           // 5 pass-2 chunks per super
constexpr int XST = 258;                    // Xs row stride (shorts): +1-pad
constexpr int PADI = 32;                    // ints per counter slot (128B line)
constexpr int PART_BLOCKS = (NE + PB - 1) / PB;   // 196
constexpr int WPK_BLOCKS  = 16;
constexpr int CVT_BLOCKS  = NN * D / 8 / 256;     // 6250

typedef __attribute__((ext_vector_type(8))) short short8;   // 8 bf16 (4 VGPR)
typedef __attribute__((ext_vector_type(4))) float floatx4;  // MFMA C/D
typedef __attribute__((ext_vector_type(2))) float floatx2;

static __device__ __forceinline__ unsigned short f2bf(float f) {
    unsigned u = __float_as_uint(f);
    unsigned r = ((u >> 16) & 1u) + 0x7fffu;
    return (unsigned short)((u + r) >> 16);
}

// ---------------------------------------------------------------------------
// k_prep: blocks [0,196): pass-1 super-bucket partition (LDS sort, coalesced
// run writes); [196,212): pack Wcat bf16; [212,6462): h fp32 -> fp8 stream.
// ---------------------------------------------------------------------------
__global__ __launch_bounds__(256) void k_prep(
    const float* __restrict__ h, const float* __restrict__ Wself,
    const float* __restrict__ Wneigh, const int* __restrict__ src,
    const int* __restrict__ dst, uint2* __restrict__ hf8,
    unsigned short* __restrict__ Wp, int* __restrict__ scnt,
    unsigned* __restrict__ packed1)
{
    const int t = threadIdx.x;
    if (blockIdx.x < PART_BLOCKS) {
        __shared__ unsigned srt[PB];              // 32 KiB
        __shared__ int sh[NS], sbeg[NS], scur[NS], sgb[NS];
        const int e0 = blockIdx.x * PB;
        const int total = min(PB, NE - e0);

        for (int i = t; i < NS; i += 256) sh[i] = 0;
        __syncthreads();

        int myd[32], msrc[32];
#pragma unroll
        for (int j = 0; j < 32; ++j) {
            int e = e0 + j * 256 + t;
            myd[j] = (e < NE) ? dst[e] : -1;
        }
#pragma unroll
        for (int j = 0; j < 32; ++j) {
            int e = e0 + j * 256 + t;
            msrc[j] = (e < NE) ? src[e] : 0;
        }
#pragma unroll
        for (int j = 0; j < 32; ++j)
            if (myd[j] >= 0) atomicAdd(&sh[myd[j] >> 11], 1);
        __syncthreads();
        if (t < 64) {                              // wave-0 scan over 49
            int v = (t < NS) ? sh[t] : 0;
            int sum = v;
#pragma unroll
            for (int off = 1; off < 64; off <<= 1) {
                int u = __shfl_up(sum, off, 64);
                if (t >= off) sum += u;
            }
            if (t < NS) {
                sbeg[t] = sum - v;
                scur[t] = sum - v;
                sgb[t]  = v ? atomicAdd(&scnt[(size_t)t * PADI], v) : 0;
            }
        }
        __syncthreads();
#pragma unroll
        for (int j = 0; j < 32; ++j) {
            if (myd[j] >= 0) {
                int s = myd[j] >> 11;
                int p = atomicAdd(&scur[s], 1);
                srt[p] = (unsigned)msrc[j] | ((unsigned)(myd[j] & 2047) << 17);
            }
        }
        __syncthreads();
        // coalesced run writes: consecutive i -> consecutive global slots
#pragma unroll
        for (int j = 0; j < 32; ++j) {
            int i = t + j * 256;
            if (i < total) {
                int lo = 0, hi = NS - 1;           // find run: sbeg[s] <= i
                while (lo < hi) {
                    int mid = (lo + hi + 1) >> 1;
                    if (sbeg[mid] <= i) lo = mid; else hi = mid - 1;
                }
                int gp = sgb[lo] + (i - sbeg[lo]);
                if (gp < CAPS)
                    packed1[(size_t)lo * CAPS + gp] = srt[i];
            }
        }
    } else if (blockIdx.x < PART_BLOCKS + WPK_BLOCKS) {
        int kg  = (blockIdx.x - PART_BLOCKS) * 2 + (t >> 7);   // 0..31
        int col = t & 127;
        unsigned short v[8];
#pragma unroll
        for (int j = 0; j < 8; ++j) {
            int k = kg * 8 + j;
            const float* W = (k < 128) ? (Wself + (size_t)k * D)
                                       : (Wneigh + (size_t)(k - 128) * D);
            v[j] = f2bf(W[col]);
        }
        uint4 o;
        o.x = (unsigned)v[0] | ((unsigned)v[1] << 16);
        o.y = (unsigned)v[2] | ((unsigned)v[3] << 16);
        o.z = (unsigned)v[4] | ((unsigned)v[5] << 16);
        o.w = (unsigned)v[6] | ((unsigned)v[7] << 16);
        ((uint4*)Wp)[kg * 128 + col] = o;
    } else {
        int i = (blockIdx.x - PART_BLOCKS - WPK_BLOCKS) * 256 + t;
        const float4* h4 = (const float4*)h;
        float4 a = h4[(size_t)i * 2];
        float4 b = h4[(size_t)i * 2 + 1];
        unsigned q0 = __builtin_amdgcn_cvt_pk_fp8_f32(a.x, a.y, 0u, false);
        q0          = __builtin_amdgcn_cvt_pk_fp8_f32(a.z, a.w, q0, true);
        unsigned q1 = __builtin_amdgcn_cvt_pk_fp8_f32(b.x, b.y, 0u, false);
        q1          = __builtin_amdgcn_cvt_pk_fp8_f32(b.z, b.w, q1, true);
        hf8[i] = make_uint2(q0, q1);
    }
}

// ---------------------------------------------------------------------------
// k_part2: (super, chunk) blocks split each super-bucket into its 32 fine
// buckets. Contiguous chunk read, 32-wide LDS sort, ~1KB coalesced run
// appends; fine-cursor contention ~5 blocks. Output = k_agg's packed format.
// ---------------------------------------------------------------------------
__global__ __launch_bounds__(256) void k_part2(
    const unsigned* __restrict__ packed1, const int* __restrict__ scnt,
    int* __restrict__ bcursor, unsigned* __restrict__ packed2)
{
    const int t  = threadIdx.x;
    const int sb = blockIdx.x / CHUNKS;
    const int ck = blockIdx.x % CHUNKS;
    const int sc = min(scnt[(size_t)sb * PADI], CAPS);
    const int beg = ck * PB;
    const int m  = min(PB, sc - beg);
    if (m <= 0) return;                            // block-uniform

    __shared__ unsigned srt[PB];                   // 32 KiB
    __shared__ int fh[32], fbeg[32], fcur[32], fgb[32];

    if (t < 32) fh[t] = 0;
    __syncthreads();

    unsigned v[32];
#pragma unroll
    for (int j = 0; j < 32; ++j) {
        int idx = t + j * 256;
        v[j] = (idx < m) ? packed1[(size_t)sb * CAPS + beg + idx] : 0xFFFFFFFFu;
    }
#pragma unroll
    for (int j = 0; j < 32; ++j) {
        int idx = t + j * 256;
        if (idx < m) atomicAdd(&fh[(v[j] >> 23) & 31u], 1);
    }
    __syncthreads();
    if (t < 32) {                                  // 32-wide scan + reserve
        int c = fh[t];
        int sum = c;
#pragma unroll
        for (int off = 1; off < 32; off <<= 1) {
            int u = __shfl_up(sum, off, 64);
            if (t >= off) sum += u;
        }
        fbeg[t] = sum - c;
        fcur[t] = sum - c;
        int b = sb * 32 + t;                       // fine bucket id (= dst>>6)
        fgb[t] = (c && b < NB) ? atomicAdd(&bcursor[(size_t)b * PADI], c) : 0;
    }
    __syncthreads();
#pragma unroll
    for (int j = 0; j < 32; ++j) {
        int idx = t + j * 256;
        if (idx < m) {
            int p = atomicAdd(&fcur[(v[j] >> 23) & 31u], 1);
            srt[p] = v[j];
        }
    }
    __syncthreads();
#pragma unroll
    for (int j = 0; j < 32; ++j) {
        int i = t + j * 256;
        if (i < m) {
            unsigned w = srt[i];
            int f  = (w >> 23) & 31u;
            int gp = fgb[f] + (i - fbeg[f]);
            if (gp < CAPB)
                packed2[(size_t)(sb * 32 + f) * CAPB + gp] = w & 0x7FFFFFu;
        }
    }
}

// ---------------------------------------------------------------------------
// Fused per-bucket kernel, 512 threads (UNCHANGED from R14, proven ~60us):
//   Phase 0: self rows fp32 -> bf16 -> Xs cols 0..127.
//   Phase A: counting-sort bucket edges into LDS (by dst&63).
//   Phase B: fp8 gather — 64 groups x 8 lanes, uint4 loads, 6-deep chains.
//   Phase C: pure-LDS MFMA out[64x128] = Xs(64x256) @ Wcat, 8 waves.
// ---------------------------------------------------------------------------
__global__ __launch_bounds__(512) void k_agg_gemm(
    const float* __restrict__ h, const uint2* __restrict__ hf8,
    const int* __restrict__ bcursor, const unsigned* __restrict__ packed,
    const unsigned short* __restrict__ Wp, float* __restrict__ out)
{
    __shared__ unsigned short Xs[BK][XST];
    __shared__ unsigned sorted[CAPB];
    __shared__ int cnt[BK], offs[BK], cur[BK];

    const int t      = threadIdx.x;
    const int bucket = blockIdx.x;
    const size_t ebeg = (size_t)bucket * CAPB;
    const int ecnt   = min(bcursor[(size_t)bucket * PADI], CAPB);

    if (t < BK) cnt[t] = 0;

    {
        int row = t >> 3, seg = t & 7;
        int grow = min(bucket * BK + row, NN - 1);
        const float4* hp = (const float4*)(h + (size_t)grow * D + seg * 16);
        float4 f0 = hp[0], f1 = hp[1], f2 = hp[2], f3 = hp[3];
        uint4 q0, q1;
        q0.x = (unsigned)f2bf(f0.x) | ((unsigned)f2bf(f0.y) << 16);
        q0.y = (unsigned)f2bf(f0.z) | ((unsigned)f2bf(f0.w) << 16);
        q0.z = (unsigned)f2bf(f1.x) | ((unsigned)f2bf(f1.y) << 16);
        q0.w = (unsigned)f2bf(f1.z) | ((unsigned)f2bf(f1.w) << 16);
        q1.x = (unsigned)f2bf(f2.x) | ((unsigned)f2bf(f2.y) << 16);
        q1.y = (unsigned)f2bf(f2.z) | ((unsigned)f2bf(f2.w) << 16);
        q1.z = (unsigned)f2bf(f3.x) | ((unsigned)f2bf(f3.y) << 16);
        q1.w = (unsigned)f2bf(f3.z) | ((unsigned)f2bf(f3.w) << 16);
        *(uint4*)&Xs[row][seg * 16]     = q0;
        *(uint4*)&Xs[row][seg * 16 + 8] = q1;
    }
    __syncthreads();

    unsigned pk[3];
#pragma unroll
    for (int i = 0; i < 3; ++i) {
        int idx = t + i * 512;
        pk[i] = (idx < ecnt) ? packed[ebeg + idx] : 0u;
    }
#pragma unroll
    for (int i = 0; i < 3; ++i) {
        int idx = t + i * 512;
        if (idx < ecnt) atomicAdd(&cnt[(pk[i] >> 17) & 63u], 1);
    }
    __syncthreads();
    if (t < BK) {
        int v = cnt[t];
        int sum = v;
#pragma unroll
        for (int off = 1; off < 64; off <<= 1) {
            int u = __shfl_up(sum, off, 64);
            if (t >= off) sum += u;
        }
        offs[t] = sum - v;
        cur[t]  = sum - v;
    }
    __syncthreads();
#pragma unroll
    for (int i = 0; i < 3; ++i) {
        int idx = t + i * 512;
        if (idx < ecnt) {
            int pos = atomicAdd(&cur[(pk[i] >> 17) & 63u], 1);
            sorted[pos] = pk[i] & 0x1FFFFu;
        }
    }
    __syncthreads();

    {
        const int g  = t >> 3;
        const int l8 = t & 7;
        const int beg = offs[g];
        const int n   = cnt[g];
        const uint4* __restrict__ hr = (const uint4*)hf8;

        floatx2 ac[8];
#pragma unroll
        for (int j = 0; j < 8; ++j) ac[j] = (floatx2){0.f, 0.f};

#define ACC16(X) do {                                                         \
            unsigned ww0 = (X).x, ww1 = (X).y, ww2 = (X).z, ww3 = (X).w;      \
            ac[0] += __builtin_amdgcn_cvt_pk_f32_fp8(ww0, false);             \
            ac[1] += __builtin_amdgcn_cvt_pk_f32_fp8(ww0, true);              \
            ac[2] += __builtin_amdgcn_cvt_pk_f32_fp8(ww1, false);             \
            ac[3] += __builtin_amdgcn_cvt_pk_f32_fp8(ww1, true);              \
            ac[4] += __builtin_amdgcn_cvt_pk_f32_fp8(ww2, false);             \
            ac[5] += __builtin_amdgcn_cvt_pk_f32_fp8(ww2, true);              \
            ac[6] += __builtin_amdgcn_cvt_pk_f32_fp8(ww3, false);             \
            ac[7] += __builtin_amdgcn_cvt_pk_f32_fp8(ww3, true);              \
        } while (0)

        int e = 0;
        for (; e + 5 < n; e += 6) {
            uint4 x0 = hr[(size_t)sorted[beg + e]     * 8 + l8];
            uint4 x1 = hr[(size_t)sorted[beg + e + 1] * 8 + l8];
            uint4 x2 = hr[(size_t)sorted[beg + e + 2] * 8 + l8];
            uint4 x3 = hr[(size_t)sorted[beg + e + 3] * 8 + l8];
            uint4 x4 = hr[(size_t)sorted[beg + e + 4] * 8 + l8];
            uint4 x5 = hr[(size_t)sorted[beg + e + 5] * 8 + l8];
            ACC16(x0); ACC16(x1); ACC16(x2);
            ACC16(x3); ACC16(x4); ACC16(x5);
        }
        for (; e + 1 < n; e += 2) {
            uint4 x0 = hr[(size_t)sorted[beg + e]     * 8 + l8];
            uint4 x1 = hr[(size_t)sorted[beg + e + 1] * 8 + l8];
            ACC16(x0); ACC16(x1);
        }
        if (e < n) {
            uint4 x0 = hr[(size_t)sorted[beg + e] * 8 + l8];
            ACC16(x0);
        }
#undef ACC16

        float inv = (n > 0) ? 1.0f / (float)n : 0.0f;
        unsigned short m[16];
#pragma unroll
        for (int j = 0; j < 8; ++j) {
            m[j * 2]     = f2bf(ac[j].x * inv);
            m[j * 2 + 1] = f2bf(ac[j].y * inv);
        }
        uint4 o0, o1;
        o0.x = (unsigned)m[0]  | ((unsigned)m[1]  << 16);
        o0.y = (unsigned)m[2]  | ((unsigned)m[3]  << 16);
        o0.z = (unsigned)m[4]  | ((unsigned)m[5]  << 16);
        o0.w = (unsigned)m[6]  | ((unsigned)m[7]  << 16);
        o1.x = (unsigned)m[8]  | ((unsigned)m[9]  << 16);
        o1.y = (unsigned)m[10] | ((unsigned)m[11] << 16);
        o1.z = (unsigned)m[12] | ((unsigned)m[13] << 16);
        o1.w = (unsigned)m[14] | ((unsigned)m[15] << 16);
        *(uint4*)&Xs[g][128 + l8 * 16]     = o0;
        *(uint4*)&Xs[g][128 + l8 * 16 + 8] = o1;
    }
    __syncthreads();

    const int wave  = t >> 6;
    const int lane  = t & 63;
    const int wl16  = lane & 15;
    const int kg4   = lane >> 4;
    const int wrow  = wave & 3;
    const int chalf = wave >> 2;
    floatx4 acc[4];
#pragma unroll
    for (int c = 0; c < 4; ++c) acc[c] = (floatx4){0.f, 0.f, 0.f, 0.f};

    const int arow = wrow * 16 + wl16;
#pragma unroll
    for (int ks = 0; ks < 8; ++ks) {
        const short8 a = *(const short8*)&Xs[arow][ks * 32 + kg4 * 8];
#pragma unroll
        for (int c = 0; c < 4; ++c) {
            const int ct = chalf * 4 + c;
            const short8 b = *(const short8*)(Wp + (((ks * 4 + kg4) * 128) + ct * 16 + wl16) * 8);
            acc[c] = __builtin_amdgcn_mfma_f32_16x16x32_bf16(a, b, acc[c], 0, 0, 0);
        }
    }

    const int rbase = bucket * BK + wrow * 16 + kg4 * 4;
#pragma unroll
    for (int r = 0; r < 4; ++r) {
        int row = rbase + r;
        if (row < NN) {
            float* o = out + (size_t)row * D + chalf * 64 + wl16;
#pragma unroll
            for (int c = 0; c < 4; ++c)
                o[c * 16] = acc[c][r];
        }
    }
}

extern "C" void kernel_launch(void* const* d_in, const int* in_sizes, int n_in,
                              void* d_out, int out_size, void* d_ws, size_t ws_size,
                              hipStream_t stream) {
    const float* h      = (const float*)d_in[0];
    const int*   src    = (const int*)d_in[1];
    const int*   dst    = (const int*)d_in[2];
    const float* Wself  = (const float*)d_in[3];
    const float* Wneigh = (const float*)d_in[4];
    float*       out    = (float*)d_out;

    // workspace layout (~31 MB)
    uint2* hf8         = (uint2*)d_ws;                                  // 12.8MB
    unsigned short* Wp = (unsigned short*)(hf8 + (size_t)NN * D / 8);   // 64KB
    unsigned* packed2  = (unsigned*)(Wp + 256 * D);                     // NB*CAPB (9.6MB)
    unsigned* packed1  = packed2 + (size_t)NB * CAPB;                   // NS*CAPS (8.0MB)
    uintptr_t bc_a     = ((uintptr_t)(packed1 + (size_t)NS * CAPS) + 255) & ~(uintptr_t)255;
    int* bcursor       = (int*)bc_a;                                    // NB*PADI (200KB)
    int* scnt          = bcursor + (size_t)NB * PADI;                   // NS*PADI (6.3KB)

    hipMemsetAsync(bcursor, 0, (size_t)(NB + NS) * PADI * sizeof(int), stream);

    k_prep     <<<dim3(PART_BLOCKS + WPK_BLOCKS + CVT_BLOCKS), 256, 0, stream>>>(
                   h, Wself, Wneigh, src, dst, hf8, Wp, scnt, packed1);
    k_part2    <<<dim3(NS * CHUNKS), 256, 0, stream>>>(packed1, scnt, bcursor, packed2);
    k_agg_gemm <<<dim3(NB), 512, 0, stream>>>(h, hf8, bcursor, packed2, Wp, out);
}

// Round 9
// 182.956 us; speedup vs baseline: 1.0302x; 1.0175x over previous
//
#include <hip/hip_runtime.h>
#include <hip/hip_cooperative_groups.h>

namespace cg = cooperative_groups;

// SAGEConv — cooperative mega-kernel: {part | Wpack | cvt} -> grid.sync ->
// grid-strided fused agg+GEMM.
// R15 post-mortem: radix partition changed NOTHING (186.1 vs 188.5), same as
// R14 split (+3) and R11 fusion (-6). Three prep restructures, three nulls ->
// prep kernels are cheap; the ~120us non-agg time is dispatch-chain overhead
// or harness-fixed. R16 forces the answer: ONE cooperative kernel = entire
// GPU-side cost visible as a single dispatch duration. bench_total - mega_dur
// = harness floor, measured decisively. Phase 2 reuses R14's proven agg body.

constexpr int NN = 100000;
constexpr int NE = 1600000;
constexpr int D  = 128;
constexpr int BK = 64;                      // nodes per bucket
constexpr int NB = (NN + BK - 1) / BK;      // 1563 buckets
constexpr int PB = 8192;                    // edges per part block
constexpr int CAPB = 1536;                  // bucket capacity (mean 1024, sd 32)
constexpr int XST = 258;                    // Xs row stride (shorts): +1-pad
constexpr int PADI = 32;                    // ints per counter slot (128B line)
constexpr int PART_BLOCKS = (NE + PB - 1) / PB;   // 196
constexpr int WPK_BLOCKS  = 8;                    // 512-thread wpack blocks
constexpr int CVT_BASE    = PART_BLOCKS + WPK_BLOCKS;  // 204
constexpr int NCVT_ITEMS  = NN * D / 8;           // 1.6M uint2

typedef __attribute__((ext_vector_type(8))) short short8;   // 8 bf16
typedef __attribute__((ext_vector_type(4))) float floatx4;  // MFMA C/D
typedef __attribute__((ext_vector_type(2))) float floatx2;

static __device__ __forceinline__ unsigned short f2bf(float f) {
    unsigned u = __float_as_uint(f);
    unsigned r = ((u >> 16) & 1u) + 0x7fffu;
    return (unsigned short)((u + r) >> 16);
}

struct SharedBlk {                     // 39,936 B -> 4 blocks/CU
    unsigned short Xs[BK][XST];        // 33,024
    unsigned sorted[CAPB];             // 6,144
    int cnt[BK], offs[BK], cur[BK];    // 768
};

// ---------------------------------------------------------------------------
// Phase-1 pieces (512-thread blocks)
// ---------------------------------------------------------------------------
static __device__ __forceinline__ void do_part(
    int t, int pb, const int* __restrict__ src, const int* __restrict__ dst,
    int* __restrict__ bcursor, unsigned* __restrict__ packed, int* lh)
{
    const int e0 = pb * PB;
    for (int i = t; i < NB; i += 512) lh[i] = 0;
    __syncthreads();

    int myd[16], msrc[16];
#pragma unroll
    for (int j = 0; j < 16; ++j) {
        int e = e0 + j * 512 + t;
        myd[j] = (e < NE) ? dst[e] : -1;
    }
#pragma unroll
    for (int j = 0; j < 16; ++j) {
        int e = e0 + j * 512 + t;
        msrc[j] = (e < NE) ? src[e] : 0;
    }
#pragma unroll
    for (int j = 0; j < 16; ++j)
        if (myd[j] >= 0) atomicAdd(&lh[myd[j] >> 6], 1);
    __syncthreads();
    for (int i = t; i < NB; i += 512) {
        int c = lh[i];
        if (c) lh[i] = atomicAdd(&bcursor[(size_t)i * PADI], c);
    }
    __syncthreads();
#pragma unroll
    for (int j = 0; j < 16; ++j) {
        if (myd[j] >= 0) {
            int b = myd[j] >> 6;
            int pos = atomicAdd(&lh[b], 1);        // global slot (lh holds base)
            if (pos < CAPB)
                packed[(size_t)b * CAPB + pos] =
                    (unsigned)msrc[j] | ((unsigned)(myd[j] & 63) << 17);
        }
    }
}

static __device__ __forceinline__ void do_wpack(
    int t, int wb, const float* __restrict__ Wself,
    const float* __restrict__ Wneigh, unsigned short* __restrict__ Wp)
{
    int kg  = wb * 4 + (t >> 7);               // 0..31
    int col = t & 127;
    unsigned short v[8];
#pragma unroll
    for (int j = 0; j < 8; ++j) {
        int k = kg * 8 + j;
        const float* W = (k < 128) ? (Wself + (size_t)k * D)
                                   : (Wneigh + (size_t)(k - 128) * D);
        v[j] = f2bf(W[col]);
    }
    uint4 o;
    o.x = (unsigned)v[0] | ((unsigned)v[1] << 16);
    o.y = (unsigned)v[2] | ((unsigned)v[3] << 16);
    o.z = (unsigned)v[4] | ((unsigned)v[5] << 16);
    o.w = (unsigned)v[6] | ((unsigned)v[7] << 16);
    ((uint4*)Wp)[kg * 128 + col] = o;
}

static __device__ __forceinline__ void do_cvt(
    int idx0, int stride, const float* __restrict__ h, uint2* __restrict__ hf8)
{
    const float4* h4 = (const float4*)h;
    for (int i = idx0; i < NCVT_ITEMS; i += stride) {
        float4 a = h4[(size_t)i * 2];
        float4 b = h4[(size_t)i * 2 + 1];
        unsigned q0 = __builtin_amdgcn_cvt_pk_fp8_f32(a.x, a.y, 0u, false);
        q0          = __builtin_amdgcn_cvt_pk_fp8_f32(a.z, a.w, q0, true);
        unsigned q1 = __builtin_amdgcn_cvt_pk_fp8_f32(b.x, b.y, 0u, false);
        q1          = __builtin_amdgcn_cvt_pk_fp8_f32(b.z, b.w, q1, true);
        hf8[i] = make_uint2(q0, q1);
    }
}

static __device__ __forceinline__ void phase1(
    int t, int b, int G,
    const float* __restrict__ h, const float* __restrict__ Wself,
    const float* __restrict__ Wneigh, const int* __restrict__ src,
    const int* __restrict__ dst, uint2* __restrict__ hf8,
    unsigned short* __restrict__ Wp, int* __restrict__ bcursor,
    unsigned* __restrict__ packed, int* lh)
{
    if (b < PART_BLOCKS) {
        do_part(t, b, src, dst, bcursor, packed, lh);
    } else if (b < CVT_BASE) {
        do_wpack(t, b - PART_BLOCKS, Wself, Wneigh, Wp);
    } else {
        int nblk = G - CVT_BASE;
        do_cvt((b - CVT_BASE) * 512 + t, nblk * 512, h, hf8);
    }
}

// ---------------------------------------------------------------------------
// Phase-2: R14's proven fused agg+GEMM body, parameterized by bucket.
// ---------------------------------------------------------------------------
static __device__ __forceinline__ void do_agg(
    int t, int bucket, const float* __restrict__ h,
    const uint2* __restrict__ hf8, const int* __restrict__ bcursor,
    const unsigned* __restrict__ packed, const unsigned short* __restrict__ Wp,
    float* __restrict__ out, SharedBlk& S)
{
    const size_t ebeg = (size_t)bucket * CAPB;
    const int ecnt   = min(bcursor[(size_t)bucket * PADI], CAPB);

    if (t < BK) S.cnt[t] = 0;

    {   // Phase 0: self rows fp32 -> bf16 into Xs cols 0..127
        int row = t >> 3, seg = t & 7;
        int grow = min(bucket * BK + row, NN - 1);
        const float4* hp = (const float4*)(h + (size_t)grow * D + seg * 16);
        float4 f0 = hp[0], f1 = hp[1], f2 = hp[2], f3 = hp[3];
        uint4 q0, q1;
        q0.x = (unsigned)f2bf(f0.x) | ((unsigned)f2bf(f0.y) << 16);
        q0.y = (unsigned)f2bf(f0.z) | ((unsigned)f2bf(f0.w) << 16);
        q0.z = (unsigned)f2bf(f1.x) | ((unsigned)f2bf(f1.y) << 16);
        q0.w = (unsigned)f2bf(f1.z) | ((unsigned)f2bf(f1.w) << 16);
        q1.x = (unsigned)f2bf(f2.x) | ((unsigned)f2bf(f2.y) << 16);
        q1.y = (unsigned)f2bf(f2.z) | ((unsigned)f2bf(f2.w) << 16);
        q1.z = (unsigned)f2bf(f3.x) | ((unsigned)f2bf(f3.y) << 16);
        q1.w = (unsigned)f2bf(f3.z) | ((unsigned)f2bf(f3.w) << 16);
        *(uint4*)&S.Xs[row][seg * 16]     = q0;
        *(uint4*)&S.Xs[row][seg * 16 + 8] = q1;
    }
    __syncthreads();

    // Phase A: counting sort of the bucket's edges into LDS
    unsigned pk[3];
#pragma unroll
    for (int i = 0; i < 3; ++i) {
        int idx = t + i * 512;
        pk[i] = (idx < ecnt) ? packed[ebeg + idx] : 0u;
    }
#pragma unroll
    for (int i = 0; i < 3; ++i) {
        int idx = t + i * 512;
        if (idx < ecnt) atomicAdd(&S.cnt[(pk[i] >> 17) & 63u], 1);
    }
    __syncthreads();
    if (t < BK) {
        int v = S.cnt[t];
        int sum = v;
#pragma unroll
        for (int off = 1; off < 64; off <<= 1) {
            int u = __shfl_up(sum, off, 64);
            if (t >= off) sum += u;
        }
        S.offs[t] = sum - v;
        S.cur[t]  = sum - v;
    }
    __syncthreads();
#pragma unroll
    for (int i = 0; i < 3; ++i) {
        int idx = t + i * 512;
        if (idx < ecnt) {
            int pos = atomicAdd(&S.cur[(pk[i] >> 17) & 63u], 1);
            S.sorted[pos] = pk[i] & 0x1FFFFu;
        }
    }
    __syncthreads();

    {   // Phase B: fp8 gather, 8-lane groups, 6-deep, pk accumulate
        const int g  = t >> 3;
        const int l8 = t & 7;
        const int beg = S.offs[g];
        const int n   = S.cnt[g];
        const uint4* __restrict__ hr = (const uint4*)hf8;

        floatx2 ac[8];
#pragma unroll
        for (int j = 0; j < 8; ++j) ac[j] = (floatx2){0.f, 0.f};

#define ACC16(X) do {                                                         \
            unsigned ww0 = (X).x, ww1 = (X).y, ww2 = (X).z, ww3 = (X).w;      \
            ac[0] += __builtin_amdgcn_cvt_pk_f32_fp8(ww0, false);             \
            ac[1] += __builtin_amdgcn_cvt_pk_f32_fp8(ww0, true);              \
            ac[2] += __builtin_amdgcn_cvt_pk_f32_fp8(ww1, false);             \
            ac[3] += __builtin_amdgcn_cvt_pk_f32_fp8(ww1, true);              \
            ac[4] += __builtin_amdgcn_cvt_pk_f32_fp8(ww2, false);             \
            ac[5] += __builtin_amdgcn_cvt_pk_f32_fp8(ww2, true);              \
            ac[6] += __builtin_amdgcn_cvt_pk_f32_fp8(ww3, false);             \
            ac[7] += __builtin_amdgcn_cvt_pk_f32_fp8(ww3, true);              \
        } while (0)

        int e = 0;
        for (; e + 5 < n; e += 6) {
            uint4 x0 = hr[(size_t)S.sorted[beg + e]     * 8 + l8];
            uint4 x1 = hr[(size_t)S.sorted[beg + e + 1] * 8 + l8];
            uint4 x2 = hr[(size_t)S.sorted[beg + e + 2] * 8 + l8];
            uint4 x3 = hr[(size_t)S.sorted[beg + e + 3] * 8 + l8];
            uint4 x4 = hr[(size_t)S.sorted[beg + e + 4] * 8 + l8];
            uint4 x5 = hr[(size_t)S.sorted[beg + e + 5] * 8 + l8];
            ACC16(x0); ACC16(x1); ACC16(x2);
            ACC16(x3); ACC16(x4); ACC16(x5);
        }
        for (; e + 1 < n; e += 2) {
            uint4 x0 = hr[(size_t)S.sorted[beg + e]     * 8 + l8];
            uint4 x1 = hr[(size_t)S.sorted[beg + e + 1] * 8 + l8];
            ACC16(x0); ACC16(x1);
        }
        if (e < n) {
            uint4 x0 = hr[(size_t)S.sorted[beg + e] * 8 + l8];
            ACC16(x0);
        }
#undef ACC16

        float inv = (n > 0) ? 1.0f / (float)n : 0.0f;
        unsigned short m[16];
#pragma unroll
        for (int j = 0; j < 8; ++j) {
            m[j * 2]     = f2bf(ac[j].x * inv);
            m[j * 2 + 1] = f2bf(ac[j].y * inv);
        }
        uint4 o0, o1;
        o0.x = (unsigned)m[0]  | ((unsigned)m[1]  << 16);
        o0.y = (unsigned)m[2]  | ((unsigned)m[3]  << 16);
        o0.z = (unsigned)m[4]  | ((unsigned)m[5]  << 16);
        o0.w = (unsigned)m[6]  | ((unsigned)m[7]  << 16);
        o1.x = (unsigned)m[8]  | ((unsigned)m[9]  << 16);
        o1.y = (unsigned)m[10] | ((unsigned)m[11] << 16);
        o1.z = (unsigned)m[12] | ((unsigned)m[13] << 16);
        o1.w = (unsigned)m[14] | ((unsigned)m[15] << 16);
        *(uint4*)&S.Xs[g][128 + l8 * 16]     = o0;
        *(uint4*)&S.Xs[g][128 + l8 * 16 + 8] = o1;
    }
    __syncthreads();

    // Phase C: MFMA out[64x128] = Xs(64x256) @ Wcat(256x128), 8 waves
    const int wave  = t >> 6;
    const int lane  = t & 63;
    const int wl16  = lane & 15;
    const int kg4   = lane >> 4;
    const int wrow  = wave & 3;
    const int chalf = wave >> 2;
    floatx4 acc[4];
#pragma unroll
    for (int c = 0; c < 4; ++c) acc[c] = (floatx4){0.f, 0.f, 0.f, 0.f};

    const int arow = wrow * 16 + wl16;
#pragma unroll
    for (int ks = 0; ks < 8; ++ks) {
        const short8 a = *(const short8*)&S.Xs[arow][ks * 32 + kg4 * 8];
#pragma unroll
        for (int c = 0; c < 4; ++c) {
            const int ct = chalf * 4 + c;
            const short8 b = *(const short8*)(Wp + (((ks * 4 + kg4) * 128) + ct * 16 + wl16) * 8);
            acc[c] = __builtin_amdgcn_mfma_f32_16x16x32_bf16(a, b, acc[c], 0, 0, 0);
        }
    }

    const int rbase = bucket * BK + wrow * 16 + kg4 * 4;
#pragma unroll
    for (int r = 0; r < 4; ++r) {
        int row = rbase + r;
        if (row < NN) {
            float* o = out + (size_t)row * D + chalf * 64 + wl16;
#pragma unroll
            for (int c = 0; c < 4; ++c)
                o[c * 16] = acc[c][r];
        }
    }
}

// ---------------------------------------------------------------------------
// Cooperative mega-kernel: phase1 -> grid.sync -> grid-strided agg.
// ---------------------------------------------------------------------------
__global__ __launch_bounds__(512) void mega(
    const float* __restrict__ h, const float* __restrict__ Wself,
    const float* __restrict__ Wneigh, const int* __restrict__ src,
    const int* __restrict__ dst, uint2* __restrict__ hf8,
    unsigned short* __restrict__ Wp, int* __restrict__ bcursor,
    unsigned* __restrict__ packed, float* __restrict__ out)
{
    __shared__ SharedBlk S;
    const int t = threadIdx.x;
    const int b = blockIdx.x;
    const int G = gridDim.x;

    phase1(t, b, G, h, Wself, Wneigh, src, dst, hf8, Wp, bcursor, packed,
           (int*)&S);
    __threadfence();                         // device-visible before sync
    cg::this_grid().sync();

    for (int bucket = b; bucket < NB; bucket += G) {
        do_agg(t, bucket, h, hf8, bcursor, packed, Wp, out, S);
        __syncthreads();                     // protect Xs reuse across buckets
    }
}

// ---------------------------------------------------------------------------
// Fallback path (if cooperative launch unavailable): 2 ordinary kernels.
// ---------------------------------------------------------------------------
constexpr int FB_PREP_G = CVT_BASE + 800;    // 1004 blocks

__global__ __launch_bounds__(512) void k_prep_fb(
    const float* __restrict__ h, const float* __restrict__ Wself,
    const float* __restrict__ Wneigh, const int* __restrict__ src,
    const int* __restrict__ dst, uint2* __restrict__ hf8,
    unsigned short* __restrict__ Wp, int* __restrict__ bcursor,
    unsigned* __restrict__ packed)
{
    __shared__ SharedBlk S;
    phase1(threadIdx.x, blockIdx.x, (int)gridDim.x, h, Wself, Wneigh, src, dst,
           hf8, Wp, bcursor, packed, (int*)&S);
}

__global__ __launch_bounds__(512) void k_agg_fb(
    const float* __restrict__ h, const uint2* __restrict__ hf8,
    const int* __restrict__ bcursor, const unsigned* __restrict__ packed,
    const unsigned short* __restrict__ Wp, float* __restrict__ out)
{
    __shared__ SharedBlk S;
    do_agg(threadIdx.x, blockIdx.x, h, hf8, bcursor, packed, Wp, out, S);
}

extern "C" void kernel_launch(void* const* d_in, const int* in_sizes, int n_in,
                              void* d_out, int out_size, void* d_ws, size_t ws_size,
                              hipStream_t stream) {
    const float* h      = (const float*)d_in[0];
    const int*   src    = (const int*)d_in[1];
    const int*   dst    = (const int*)d_in[2];
    const float* Wself  = (const float*)d_in[3];
    const float* Wneigh = (const float*)d_in[4];
    float*       out    = (float*)d_out;

    // workspace layout (~22.7 MB)
    uint2* hf8         = (uint2*)d_ws;                                  // 12.8MB
    unsigned short* Wp = (unsigned short*)(hf8 + (size_t)NN * D / 8);   // 64KB
    unsigned* packed   = (unsigned*)(Wp + 256 * D);                     // 9.6MB
    uintptr_t bc_a     = ((uintptr_t)(packed + (size_t)NB * CAPB) + 255) & ~(uintptr_t)255;
    int* bcursor       = (int*)bc_a;                                    // 200KB

    hipMemsetAsync(bcursor, 0, (size_t)NB * PADI * sizeof(int), stream);

    int mablk = 0;
    hipError_t oe = hipOccupancyMaxActiveBlocksPerMultiprocessor(&mablk, mega, 512, 0);
    int G = (oe == hipSuccess && mablk >= 1) ? mablk * 256 : 0;
    if (G > 1024) G = 1024;

    hipError_t le = hipErrorUnknown;
    if (G >= 256) {
        void* args[] = {(void*)&h, (void*)&Wself, (void*)&Wneigh, (void*)&src,
                        (void*)&dst, (void*)&hf8, (void*)&Wp, (void*)&bcursor,
                        (void*)&packed, (void*)&out};
        le = hipLaunchCooperativeKernel(mega, dim3(G), dim3(512), args, 0u, stream);
    }
    if (le != hipSuccess) {
        k_prep_fb<<<dim3(FB_PREP_G), 512, 0, stream>>>(
            h, Wself, Wneigh, src, dst, hf8, Wp, bcursor, packed);
        k_agg_fb <<<dim3(NB), 512, 0, stream>>>(h, hf8, bcursor, packed, Wp, out);
    }
}